// Round 13
// baseline (51.612 us; speedup 1.0000x reference)
//
#include <hip/hip_runtime.h>
#include <math.h>

#define H 256
#define EPS 1e-4f

// ---- DPP helpers (gfx9/CDNA), bound_ctrl:0 (0-fill invalid lanes) ----
template <int CTRL>
__device__ __forceinline__ float dpp0(float x) {
    return __int_as_float(
        __builtin_amdgcn_update_dpp(0, __float_as_int(x), CTRL, 0xf, 0xf, true));
}
__device__ __forceinline__ float rdlane(float x, int l) {
    return __int_as_float(__builtin_amdgcn_readlane(__float_as_int(x), l));
}
__device__ __forceinline__ float frcp_fast(float v) { return __builtin_amdgcn_rcpf(v); }
__device__ __forceinline__ float frcp_nr(float v) {
    float r = __builtin_amdgcn_rcpf(v);
    return fmaf(r, fmaf(-v, r, 1.0f), r);
}
// full-wave sum of two values, result uniform
__device__ __forceinline__ void wave_red_sum2(float& a, float& b) {
    a += dpp0<0x111>(a);  b += dpp0<0x111>(b);
    a += dpp0<0x112>(a);  b += dpp0<0x112>(b);
    a += dpp0<0x114>(a);  b += dpp0<0x114>(b);
    a += dpp0<0x118>(a);  b += dpp0<0x118>(b);
    a += dpp0<0x142>(a);  b += dpp0<0x142>(b);
    a += dpp0<0x143>(a);  b += dpp0<0x143>(b);
    a = rdlane(a, 63);
    b = rdlane(b, 63);
}

// Support-packed Schur step k -> k+1 (identical arithmetic to R12).
// P = a|F, Q = ra|B, X = x|-R;  P' = P + g*sh1(Q);  Q' = sh1(Q) + g*P;
// X' = X + mu*Q'.  Boundary: P'[k+1] <- g, X'[k+1] <- mu via cmp+cndmask.
#define STEP(KF1, KF2, LN1, LN2) do {                                   \
    float g  = -sF * isB;                                               \
    float sE = fmaf(g, sF, sB);              /* B_{k+1}[k+1] */         \
    isB = frcp_fast(sE);                                                \
    float mu = -sRt * isB;                                              \
    float rlF2 = rdlane(P[KF2], (LN2));      /* F_k[k+2]  */            \
    float rlB1 = rdlane(Q[KF1], (LN1));      /* B_k[k+1]  */            \
    float rlR2 = rdlane(X[KF2], (LN2));      /* -R_k[k+2] */            \
    sF  = fmaf(g, rlB1, rlF2);               /* F_{k+1}[k+2] */         \
    float tB2 = fmaf(g, rlF2, rlB1);         /* B_{k+1}[k+2] */         \
    sRt = fmaf(mu, tB2, rlR2);               /* -R_{k+1}[k+2] */        \
    sB  = sE;                                                           \
    float shq0 = dpp0<0x138>(Q[3]);          /* wave_shr:1 */           \
    float nQ0 = fmaf(g, P[0], shq0);                                    \
    float nQ1 = fmaf(g, P[1], Q[0]);                                    \
    float nQ2 = fmaf(g, P[2], Q[1]);                                    \
    float nQ3 = fmaf(g, P[3], Q[2]);                                    \
    float nP0 = fmaf(g, shq0, P[0]);                                    \
    float nP1 = fmaf(g, Q[0],  P[1]);                                   \
    float nP2 = fmaf(g, Q[1],  P[2]);                                   \
    float nP3 = fmaf(g, Q[2],  P[3]);                                   \
    X[0] = fmaf(mu, nQ0, X[0]);                                         \
    X[1] = fmaf(mu, nQ1, X[1]);                                         \
    X[2] = fmaf(mu, nQ2, X[2]);                                         \
    X[3] = fmaf(mu, nQ3, X[3]);                                         \
    bool bm = (lane == (LN1));               /* element k+1's lane */   \
    P[0]=nP0; P[1]=nP1; P[2]=nP2; P[3]=nP3;                             \
    Q[0]=nQ0; Q[1]=nQ1; Q[2]=nQ2; Q[3]=nQ3;                             \
    P[KF1] = bm ? g  : P[KF1];                                          \
    X[KF1] = bm ? mu : X[KF1];                                          \
} while (0)

// 8 waves/block, one batch per wave; 64 blocks -> 1 block/CU on 64 CUs ->
// 2 waves per SIMD. Under the measured ~4cy/op single-wave cadence (R12
// delta calibration), co-resident waves interleave to ~2cy/op each.
// Packed state (~30 live floats) is small enough to fit the 32-VGPR
// allocation that 512-thread blocks get (R10/R11's 6-array state spilled).
__global__ __launch_bounds__(512, 2) void awloss_batch(
        const float* __restrict__ recon,
        const float* __restrict__ target,
        float* __restrict__ losses) {
    const int lane = threadIdx.x & 63;
    const int wid  = threadIdx.x >> 6;
    const int b    = blockIdx.x * 8 + wid;
    const bool l0  = (lane == 0);

    __shared__ __align__(16) float tgtp_s[8][576];
    __shared__ __align__(16) float recp_s[8][576];
    float* tgtp = tgtp_s[wid];
    float* recp = recp_s[wid];

    const float4 tv4 = ((const float4*)(target + b * H))[lane];
    const float4 rv4 = ((const float4*)(recon  + b * H))[lane];

    #pragma unroll
    for (int c = 0; c < 9; ++c) { tgtp[c*64+lane] = 0.f; recp[c*64+lane] = 0.f; }
    __syncthreads();
    *(float4*)&tgtp[4*lane] = tv4;
    recp[127 + 4*lane + 0] = rv4.x;
    recp[127 + 4*lane + 1] = rv4.y;
    recp[127 + 4*lane + 2] = rv4.z;
    recp[127 + 4*lane + 3] = rv4.w;
    __syncthreads();

    // --- correlation r[d], b[d], lane-major d = 4*lane+c; b128 sliding window ---
    float racc[4] = {0.f,0.f,0.f,0.f}, bacc[4] = {0.f,0.f,0.f,0.f};
    float4 W0t = *(const float4*)&tgtp[4*lane];
    float4 W0r = *(const float4*)&recp[4*lane];
    for (int m0 = 0; m0 < 256; m0 += 4) {
        float4 W1t = *(const float4*)&tgtp[m0 + 4 + 4*lane];
        float4 W1r = *(const float4*)&recp[m0 + 4 + 4*lane];
        float t0s = rdlane(W0t.x, 0);
        float t1s = rdlane(W0t.y, 0);
        float t2s = rdlane(W0t.z, 0);
        float t3s = rdlane(W0t.w, 0);
        racc[0] = fmaf(t0s, W0t.x, racc[0]); bacc[0] = fmaf(t0s, W0r.x, bacc[0]);
        racc[1] = fmaf(t0s, W0t.y, racc[1]); bacc[1] = fmaf(t0s, W0r.y, bacc[1]);
        racc[2] = fmaf(t0s, W0t.z, racc[2]); bacc[2] = fmaf(t0s, W0r.z, bacc[2]);
        racc[3] = fmaf(t0s, W0t.w, racc[3]); bacc[3] = fmaf(t0s, W0r.w, bacc[3]);
        racc[0] = fmaf(t1s, W0t.y, racc[0]); bacc[0] = fmaf(t1s, W0r.y, bacc[0]);
        racc[1] = fmaf(t1s, W0t.z, racc[1]); bacc[1] = fmaf(t1s, W0r.z, bacc[1]);
        racc[2] = fmaf(t1s, W0t.w, racc[2]); bacc[2] = fmaf(t1s, W0r.w, bacc[2]);
        racc[3] = fmaf(t1s, W1t.x, racc[3]); bacc[3] = fmaf(t1s, W1r.x, bacc[3]);
        racc[0] = fmaf(t2s, W0t.z, racc[0]); bacc[0] = fmaf(t2s, W0r.z, bacc[0]);
        racc[1] = fmaf(t2s, W0t.w, racc[1]); bacc[1] = fmaf(t2s, W0r.w, bacc[1]);
        racc[2] = fmaf(t2s, W1t.x, racc[2]); bacc[2] = fmaf(t2s, W1r.x, bacc[2]);
        racc[3] = fmaf(t2s, W1t.y, racc[3]); bacc[3] = fmaf(t2s, W1r.y, bacc[3]);
        racc[0] = fmaf(t3s, W0t.w, racc[0]); bacc[0] = fmaf(t3s, W0r.w, bacc[0]);
        racc[1] = fmaf(t3s, W1t.x, racc[1]); bacc[1] = fmaf(t3s, W1r.x, bacc[1]);
        racc[2] = fmaf(t3s, W1t.y, racc[2]); bacc[2] = fmaf(t3s, W1r.y, bacc[2]);
        racc[3] = fmaf(t3s, W1t.z, racc[3]); bacc[3] = fmaf(t3s, W1r.z, bacc[3]);
        W0t = W1t; W0r = W1r;
    }

    // --- normalize; init packed state (lane-major e = 4*lane+c) ---
    float t0v = rdlane(racc[0], 0) + EPS;
    float it0 = frcp_nr(t0v);
    float P[4], Q[4], X[4];
    #pragma unroll
    for (int c = 0; c < 4; ++c) {
        float rh = racc[c] * it0;
        if (c == 0) rh = l0 ? 1.0f : rh;   // rho[0]=1; a_0[0]=1, B_0[0]=1
        P[c] = rh; Q[c] = rh;              // P = a|F = rho; Q = ra|B = rho
    }
    float bb0 = rdlane(bacc[0], 0) * it0;
    #pragma unroll
    for (int c = 0; c < 4; ++c) {
        float bvv = bacc[c] * it0;
        X[c] = fmaf(bb0, P[c], -bvv);      // -R_0 = bb0*rho - bb
    }
    if (l0) X[0] = bb0;                    // x_0[0] = bb0

    float sF  = rdlane(P[1], 0);           // F_0[1] = rho[1]
    float sB  = 1.0f, isB = 1.0f;
    float sRt = rdlane(X[1], 0);           // -R_0[1]

    // --- 255 Schur steps, x4 unrolled for literal register indices ---
    for (int t = 0; t < 63; ++t) {
        STEP(1, 2, t, t);                  // k = 4t
        STEP(2, 3, t, t);                  // k = 4t+1
        STEP(3, 0, t, t + 1);              // k = 4t+2
        STEP(0, 1, t + 1, t + 1);          // k = 4t+3
    }
    STEP(1, 2, 63, 63);                    // k = 252
    STEP(2, 3, 63, 63);                    // k = 253
    {   // k = 254: only mu and the X update matter (element 255 <- mu)
        float g  = -sF * isB;
        float sE = fmaf(g, sF, sB);
        float mu = -sRt * frcp_fast(sE);
        float shq0 = dpp0<0x138>(Q[3]);
        float nQ0 = fmaf(g, P[0], shq0);
        float nQ1 = fmaf(g, P[1], Q[0]);
        float nQ2 = fmaf(g, P[2], Q[1]);
        float nQ3 = fmaf(g, P[3], Q[2]);
        X[0] = fmaf(mu, nQ0, X[0]);
        X[1] = fmaf(mu, nQ1, X[1]);
        X[2] = fmaf(mu, nQ2, X[2]);
        X[3] = fmaf(mu, nQ3, X[3]);
        X[3] = (lane == 63) ? mu : X[3];
    }

    // --- loss: 0.5*sqrt(sum((T*v)^2)/sum(v^2)), elements e = 4*lane+c ---
    float sT = 0.f, sV = 0.f;
    const float dxg = 20.0f / 255.0f;
    #pragma unroll
    for (int c = 0; c < 4; ++c) {
        float v  = X[c];
        float u  = -10.0f + dxg * (float)(4*lane + c) + 0.5f * dxg;
        float Ti = 1.0f - expf(-0.5f * u * u);   // T normalizers == 1.0f in f32
        float tw = Ti * v;
        sT += tw * tw;
        sV += v * v;
    }
    wave_red_sum2(sT, sV);
    if (l0) losses[b] = 0.5f * sqrtf(sT / sV);
}

// deterministic final reduction of 512 per-batch losses
__global__ __launch_bounds__(64) void awloss_reduce(
        const float* __restrict__ losses, float* __restrict__ out) {
    int lane = threadIdx.x;
    float s = 0.f;
    #pragma unroll
    for (int c = 0; c < 8; ++c) s += losses[c * 64 + lane];
    float d = 0.f;
    wave_red_sum2(s, d);
    if (lane == 0) out[0] = s;
}

extern "C" void kernel_launch(void* const* d_in, const int* in_sizes, int n_in,
                              void* d_out, int out_size, void* d_ws, size_t ws_size,
                              hipStream_t stream) {
    const float* recon  = (const float*)d_in[0];
    const float* target = (const float*)d_in[1];
    float* losses = (float*)d_ws;   // 512 floats
    float* out    = (float*)d_out;

    awloss_batch<<<64, 512, 0, stream>>>(recon, target, losses);
    awloss_reduce<<<1, 64, 0, stream>>>(losses, out);
}

// Round 14
// 42.481 us; speedup vs baseline: 1.2150x; 1.2150x over previous
//
#include <hip/hip_runtime.h>
#include <math.h>

#define H 256
#define EPS 1e-4f

// ---- DPP helpers (gfx9/CDNA), bound_ctrl:0 (0-fill invalid lanes) ----
template <int CTRL>
__device__ __forceinline__ float dpp0(float x) {
    return __int_as_float(
        __builtin_amdgcn_update_dpp(0, __float_as_int(x), CTRL, 0xf, 0xf, true));
}
__device__ __forceinline__ float rdlane(float x, int l) {
    return __int_as_float(__builtin_amdgcn_readlane(__float_as_int(x), l));
}
__device__ __forceinline__ float frcp_fast(float v) { return __builtin_amdgcn_rcpf(v); }
__device__ __forceinline__ float frcp_nr(float v) {
    float r = __builtin_amdgcn_rcpf(v);
    return fmaf(r, fmaf(-v, r, 1.0f), r);
}
// full-wave sum of four values, result uniform
__device__ __forceinline__ void wave_red_sum4(float& a, float& b, float& c, float& d) {
    a += dpp0<0x111>(a); b += dpp0<0x111>(b); c += dpp0<0x111>(c); d += dpp0<0x111>(d);
    a += dpp0<0x112>(a); b += dpp0<0x112>(b); c += dpp0<0x112>(c); d += dpp0<0x112>(d);
    a += dpp0<0x114>(a); b += dpp0<0x114>(b); c += dpp0<0x114>(c); d += dpp0<0x114>(d);
    a += dpp0<0x118>(a); b += dpp0<0x118>(b); c += dpp0<0x118>(c); d += dpp0<0x118>(d);
    a += dpp0<0x142>(a); b += dpp0<0x142>(b); c += dpp0<0x142>(c); d += dpp0<0x142>(d);
    a += dpp0<0x143>(a); b += dpp0<0x143>(b); c += dpp0<0x143>(c); d += dpp0<0x143>(d);
    a = rdlane(a, 63); b = rdlane(b, 63); c = rdlane(c, 63); d = rdlane(d, 63);
}
__device__ __forceinline__ void wave_red_sum2(float& a, float& b) {
    a += dpp0<0x111>(a);  b += dpp0<0x111>(b);
    a += dpp0<0x112>(a);  b += dpp0<0x112>(b);
    a += dpp0<0x114>(a);  b += dpp0<0x114>(b);
    a += dpp0<0x118>(a);  b += dpp0<0x118>(b);
    a += dpp0<0x142>(a);  b += dpp0<0x142>(b);
    a += dpp0<0x143>(a);  b += dpp0<0x143>(b);
    a = rdlane(a, 63);
    b = rdlane(b, 63);
}

// Support-packed Schur step k -> k+1 (arithmetic identical per-chain to R12).
// Parameterized by array/scalar names so two independent chains can be
// interleaved in ONE instruction stream (doubles dependency distance ->
// compiler fills hazard slots with the other chain's ops instead of s_nops).
#define STEP(P, Q, X, sF, sB, isB, sRt, KF1, KF2, LN1, LN2) do {        \
    float g  = -sF * isB;                                               \
    float sE = fmaf(g, sF, sB);              /* B_{k+1}[k+1] */         \
    isB = frcp_fast(sE);                                                \
    float mu = -sRt * isB;                                              \
    float rlF2 = rdlane(P[KF2], (LN2));      /* F_k[k+2]  */            \
    float rlB1 = rdlane(Q[KF1], (LN1));      /* B_k[k+1]  */            \
    float rlR2 = rdlane(X[KF2], (LN2));      /* -R_k[k+2] */            \
    sF  = fmaf(g, rlB1, rlF2);               /* F_{k+1}[k+2] */         \
    float tB2 = fmaf(g, rlF2, rlB1);         /* B_{k+1}[k+2] */         \
    sRt = fmaf(mu, tB2, rlR2);               /* -R_{k+1}[k+2] */        \
    sB  = sE;                                                           \
    float shq0 = dpp0<0x138>(Q[3]);          /* wave_shr:1 */           \
    float nQ0 = fmaf(g, P[0], shq0);                                    \
    float nQ1 = fmaf(g, P[1], Q[0]);                                    \
    float nQ2 = fmaf(g, P[2], Q[1]);                                    \
    float nQ3 = fmaf(g, P[3], Q[2]);                                    \
    float nP0 = fmaf(g, shq0, P[0]);                                    \
    float nP1 = fmaf(g, Q[0],  P[1]);                                   \
    float nP2 = fmaf(g, Q[1],  P[2]);                                   \
    float nP3 = fmaf(g, Q[2],  P[3]);                                   \
    X[0] = fmaf(mu, nQ0, X[0]);                                         \
    X[1] = fmaf(mu, nQ1, X[1]);                                         \
    X[2] = fmaf(mu, nQ2, X[2]);                                         \
    X[3] = fmaf(mu, nQ3, X[3]);                                         \
    bool bm = (lane == (LN1));               /* element k+1's lane */   \
    P[0]=nP0; P[1]=nP1; P[2]=nP2; P[3]=nP3;                             \
    Q[0]=nQ0; Q[1]=nQ1; Q[2]=nQ2; Q[3]=nQ3;                             \
    P[KF1] = bm ? g  : P[KF1];                                          \
    X[KF1] = bm ? mu : X[KF1];                                          \
} while (0)

#define STEP2(KF1, KF2, LN1, LN2)                                       \
    STEP(PA, QA, XA, sFA, sBA, isBA, sRtA, KF1, KF2, LN1, LN2);         \
    STEP(PB, QB, XB, sFB, sBB, isBB, sRtB, KF1, KF2, LN1, LN2)

// One wave per TWO batches, packed state (~50 live VGPRs -> no spill, unlike
// R6's 6-array x2 = 76 which spilled at VGPR=48). 256 blocks x 64 threads.
__global__ __launch_bounds__(64) void awloss_batch(
        const float* __restrict__ recon,
        const float* __restrict__ target,
        float* __restrict__ losses) {
    const int bp   = blockIdx.x;
    const int b0   = 2 * bp, b1 = 2 * bp + 1;
    const int lane = threadIdx.x;
    const bool l0  = (lane == 0);

    __shared__ __align__(16) float tgtA[576], recA[576], tgtB[576], recB[576];

    const float4 tvA = ((const float4*)(target + b0 * H))[lane];
    const float4 rvA = ((const float4*)(recon  + b0 * H))[lane];
    const float4 tvB = ((const float4*)(target + b1 * H))[lane];
    const float4 rvB = ((const float4*)(recon  + b1 * H))[lane];

    #pragma unroll
    for (int c = 0; c < 9; ++c) {
        tgtA[c*64+lane] = 0.f; recA[c*64+lane] = 0.f;
        tgtB[c*64+lane] = 0.f; recB[c*64+lane] = 0.f;
    }
    __syncthreads();
    *(float4*)&tgtA[4*lane] = tvA;
    *(float4*)&tgtB[4*lane] = tvB;
    recA[127+4*lane+0]=rvA.x; recA[127+4*lane+1]=rvA.y;
    recA[127+4*lane+2]=rvA.z; recA[127+4*lane+3]=rvA.w;
    recB[127+4*lane+0]=rvB.x; recB[127+4*lane+1]=rvB.y;
    recB[127+4*lane+2]=rvB.z; recB[127+4*lane+3]=rvB.w;
    __syncthreads();

    // --- correlations for both batches, interleaved (R6's proven pattern) ---
    float raA[4]={0,0,0,0}, baA[4]={0,0,0,0}, raB[4]={0,0,0,0}, baB[4]={0,0,0,0};
    float4 WtA = *(const float4*)&tgtA[4*lane];
    float4 WrA = *(const float4*)&recA[4*lane];
    float4 WtB = *(const float4*)&tgtB[4*lane];
    float4 WrB = *(const float4*)&recB[4*lane];
    for (int m0 = 0; m0 < 256; m0 += 4) {
        float4 NtA = *(const float4*)&tgtA[m0 + 4 + 4*lane];
        float4 NrA = *(const float4*)&recA[m0 + 4 + 4*lane];
        float4 NtB = *(const float4*)&tgtB[m0 + 4 + 4*lane];
        float4 NrB = *(const float4*)&recB[m0 + 4 + 4*lane];
        float a0 = rdlane(WtA.x,0), a1 = rdlane(WtA.y,0),
              a2 = rdlane(WtA.z,0), a3 = rdlane(WtA.w,0);
        float b0s= rdlane(WtB.x,0), b1s= rdlane(WtB.y,0),
              b2s= rdlane(WtB.z,0), b3s= rdlane(WtB.w,0);
        raA[0]=fmaf(a0,WtA.x,raA[0]); baA[0]=fmaf(a0,WrA.x,baA[0]);
        raB[0]=fmaf(b0s,WtB.x,raB[0]); baB[0]=fmaf(b0s,WrB.x,baB[0]);
        raA[1]=fmaf(a0,WtA.y,raA[1]); baA[1]=fmaf(a0,WrA.y,baA[1]);
        raB[1]=fmaf(b0s,WtB.y,raB[1]); baB[1]=fmaf(b0s,WrB.y,baB[1]);
        raA[2]=fmaf(a0,WtA.z,raA[2]); baA[2]=fmaf(a0,WrA.z,baA[2]);
        raB[2]=fmaf(b0s,WtB.z,raB[2]); baB[2]=fmaf(b0s,WrB.z,baB[2]);
        raA[3]=fmaf(a0,WtA.w,raA[3]); baA[3]=fmaf(a0,WrA.w,baA[3]);
        raB[3]=fmaf(b0s,WtB.w,raB[3]); baB[3]=fmaf(b0s,WrB.w,baB[3]);
        raA[0]=fmaf(a1,WtA.y,raA[0]); baA[0]=fmaf(a1,WrA.y,baA[0]);
        raB[0]=fmaf(b1s,WtB.y,raB[0]); baB[0]=fmaf(b1s,WrB.y,baB[0]);
        raA[1]=fmaf(a1,WtA.z,raA[1]); baA[1]=fmaf(a1,WrA.z,baA[1]);
        raB[1]=fmaf(b1s,WtB.z,raB[1]); baB[1]=fmaf(b1s,WrB.z,baB[1]);
        raA[2]=fmaf(a1,WtA.w,raA[2]); baA[2]=fmaf(a1,WrA.w,baA[2]);
        raB[2]=fmaf(b1s,WtB.w,raB[2]); baB[2]=fmaf(b1s,WrB.w,baB[2]);
        raA[3]=fmaf(a1,NtA.x,raA[3]); baA[3]=fmaf(a1,NrA.x,baA[3]);
        raB[3]=fmaf(b1s,NtB.x,raB[3]); baB[3]=fmaf(b1s,NrB.x,baB[3]);
        raA[0]=fmaf(a2,WtA.z,raA[0]); baA[0]=fmaf(a2,WrA.z,baA[0]);
        raB[0]=fmaf(b2s,WtB.z,raB[0]); baB[0]=fmaf(b2s,WrB.z,baB[0]);
        raA[1]=fmaf(a2,WtA.w,raA[1]); baA[1]=fmaf(a2,WrA.w,baA[1]);
        raB[1]=fmaf(b2s,WtB.w,raB[1]); baB[1]=fmaf(b2s,WrB.w,baB[1]);
        raA[2]=fmaf(a2,NtA.x,raA[2]); baA[2]=fmaf(a2,NrA.x,baA[2]);
        raB[2]=fmaf(b2s,NtB.x,raB[2]); baB[2]=fmaf(b2s,NrB.x,baB[2]);
        raA[3]=fmaf(a2,NtA.y,raA[3]); baA[3]=fmaf(a2,NrA.y,baA[3]);
        raB[3]=fmaf(b2s,NtB.y,raB[3]); baB[3]=fmaf(b2s,NrB.y,baB[3]);
        raA[0]=fmaf(a3,WtA.w,raA[0]); baA[0]=fmaf(a3,WrA.w,baA[0]);
        raB[0]=fmaf(b3s,WtB.w,raB[0]); baB[0]=fmaf(b3s,WrB.w,baB[0]);
        raA[1]=fmaf(a3,NtA.x,raA[1]); baA[1]=fmaf(a3,NrA.x,baA[1]);
        raB[1]=fmaf(b3s,NtB.x,raB[1]); baB[1]=fmaf(b3s,NrB.x,baB[1]);
        raA[2]=fmaf(a3,NtA.y,raA[2]); baA[2]=fmaf(a3,NrA.y,baA[2]);
        raB[2]=fmaf(b3s,NtB.y,raB[2]); baB[2]=fmaf(b3s,NrB.y,baB[2]);
        raA[3]=fmaf(a3,NtA.z,raA[3]); baA[3]=fmaf(a3,NrA.z,baA[3]);
        raB[3]=fmaf(b3s,NtB.z,raB[3]); baB[3]=fmaf(b3s,NrB.z,baB[3]);
        WtA = NtA; WrA = NrA; WtB = NtB; WrB = NrB;
    }

    // --- normalize; init packed states (lane-major e = 4*lane+c) ---
    float PA[4], QA[4], XA[4], PB[4], QB[4], XB[4];
    float t0A = rdlane(raA[0], 0) + EPS;
    float t0B = rdlane(raB[0], 0) + EPS;
    float itA = frcp_nr(t0A);
    float itB = frcp_nr(t0B);
    #pragma unroll
    for (int c = 0; c < 4; ++c) {
        float rhA = raA[c] * itA;
        float rhB = raB[c] * itB;
        if (c == 0) { rhA = l0 ? 1.0f : rhA; rhB = l0 ? 1.0f : rhB; }
        PA[c] = rhA; QA[c] = rhA;
        PB[c] = rhB; QB[c] = rhB;
    }
    float bb0A = rdlane(baA[0], 0) * itA;
    float bb0B = rdlane(baB[0], 0) * itB;
    #pragma unroll
    for (int c = 0; c < 4; ++c) {
        XA[c] = fmaf(bb0A, PA[c], -(baA[c] * itA));   // -R_0
        XB[c] = fmaf(bb0B, PB[c], -(baB[c] * itB));
    }
    if (l0) { XA[0] = bb0A; XB[0] = bb0B; }

    float sFA = rdlane(PA[1], 0), sFB = rdlane(PB[1], 0);
    float sBA = 1.0f, isBA = 1.0f, sBB = 1.0f, isBB = 1.0f;
    float sRtA = rdlane(XA[1], 0), sRtB = rdlane(XB[1], 0);

    // --- 255 Schur steps x 2 chains, x4 unrolled for literal reg indices ---
    for (int t = 0; t < 63; ++t) {
        STEP2(1, 2, t, t);                 // k = 4t
        STEP2(2, 3, t, t);                 // k = 4t+1
        STEP2(3, 0, t, t + 1);             // k = 4t+2
        STEP2(0, 1, t + 1, t + 1);         // k = 4t+3
    }
    STEP2(1, 2, 63, 63);                   // k = 252
    STEP2(2, 3, 63, 63);                   // k = 253
    {   // k = 254: only mu and the X update matter (element 255 <- mu)
        float gA  = -sFA * isBA;
        float gB  = -sFB * isBB;
        float sEA = fmaf(gA, sFA, sBA);
        float sEB = fmaf(gB, sFB, sBB);
        float muA = -sRtA * frcp_fast(sEA);
        float muB = -sRtB * frcp_fast(sEB);
        float shqA = dpp0<0x138>(QA[3]);
        float shqB = dpp0<0x138>(QB[3]);
        XA[0] = fmaf(muA, fmaf(gA, PA[0], shqA),  XA[0]);
        XB[0] = fmaf(muB, fmaf(gB, PB[0], shqB),  XB[0]);
        XA[1] = fmaf(muA, fmaf(gA, PA[1], QA[0]), XA[1]);
        XB[1] = fmaf(muB, fmaf(gB, PB[1], QB[0]), XB[1]);
        XA[2] = fmaf(muA, fmaf(gA, PA[2], QA[1]), XA[2]);
        XB[2] = fmaf(muB, fmaf(gB, PB[2], QB[1]), XB[2]);
        XA[3] = fmaf(muA, fmaf(gA, PA[3], QA[2]), XA[3]);
        XB[3] = fmaf(muB, fmaf(gB, PB[3], QB[2]), XB[3]);
        XA[3] = (lane == 63) ? muA : XA[3];
        XB[3] = (lane == 63) ? muB : XB[3];
    }

    // --- losses ---
    float sTA = 0.f, sVA = 0.f, sTB = 0.f, sVB = 0.f;
    const float dxg = 20.0f / 255.0f;
    #pragma unroll
    for (int c = 0; c < 4; ++c) {
        float u  = -10.0f + dxg * (float)(4*lane + c) + 0.5f * dxg;
        float Ti = 1.0f - expf(-0.5f * u * u);   // T normalizers == 1.0f in f32
        float vA = XA[c], vB = XB[c];
        float tA = Ti * vA, tB = Ti * vB;
        sTA += tA * tA;  sVA += vA * vA;
        sTB += tB * tB;  sVB += vB * vB;
    }
    wave_red_sum4(sTA, sVA, sTB, sVB);
    if (l0) {
        losses[b0] = 0.5f * sqrtf(sTA / sVA);
        losses[b1] = 0.5f * sqrtf(sTB / sVB);
    }
}

// deterministic final reduction of 512 per-batch losses
__global__ __launch_bounds__(64) void awloss_reduce(
        const float* __restrict__ losses, float* __restrict__ out) {
    int lane = threadIdx.x;
    float s = 0.f;
    #pragma unroll
    for (int c = 0; c < 8; ++c) s += losses[c * 64 + lane];
    float d = 0.f;
    wave_red_sum2(s, d);
    if (lane == 0) out[0] = s;
}

extern "C" void kernel_launch(void* const* d_in, const int* in_sizes, int n_in,
                              void* d_out, int out_size, void* d_ws, size_t ws_size,
                              hipStream_t stream) {
    const float* recon  = (const float*)d_in[0];
    const float* target = (const float*)d_in[1];
    float* losses = (float*)d_ws;   // 512 floats
    float* out    = (float*)d_out;

    awloss_batch<<<256, 64, 0, stream>>>(recon, target, losses);
    awloss_reduce<<<1, 64, 0, stream>>>(losses, out);
}

// Round 15
// 27.038 us; speedup vs baseline: 1.9089x; 1.5711x over previous
//
#include <hip/hip_runtime.h>
#include <math.h>

#define H 256
#define EPS 1e-4f

typedef float float2v __attribute__((ext_vector_type(2)));

__device__ __forceinline__ float2v pkfma(float2v a, float2v b, float2v c) {
    return __builtin_elementwise_fma(a, b, c);   // -> v_pk_fma_f32 on gfx950
}

// ---- DPP helpers (gfx9/CDNA), bound_ctrl:0 (0-fill invalid lanes) ----
template <int CTRL>
__device__ __forceinline__ float dpp0(float x) {
    return __int_as_float(
        __builtin_amdgcn_update_dpp(0, __float_as_int(x), CTRL, 0xf, 0xf, true));
}
__device__ __forceinline__ float rdlane(float x, int l) {
    return __int_as_float(__builtin_amdgcn_readlane(__float_as_int(x), l));
}
__device__ __forceinline__ float frcp_fast(float v) { return __builtin_amdgcn_rcpf(v); }
__device__ __forceinline__ float frcp_nr(float v) {
    float r = __builtin_amdgcn_rcpf(v);
    return fmaf(r, fmaf(-v, r, 1.0f), r);
}
// full-wave sum of two values, result uniform
__device__ __forceinline__ void wave_red_sum2(float& a, float& b) {
    a += dpp0<0x111>(a);  b += dpp0<0x111>(b);
    a += dpp0<0x112>(a);  b += dpp0<0x112>(b);
    a += dpp0<0x114>(a);  b += dpp0<0x114>(b);
    a += dpp0<0x118>(a);  b += dpp0<0x118>(b);
    a += dpp0<0x142>(a);  b += dpp0<0x142>(b);
    a += dpp0<0x143>(a);  b += dpp0<0x143>(b);
    a = rdlane(a, 63);
    b = rdlane(b, 63);
}

// Support-packed Schur step, STRIDE-2 PAIRED registers (bitwise-identical
// arithmetic to R12). Element e = 4*lane + c; slot->reg map:
//   c=0 -> p0.x, c=1 -> p1.x, c=2 -> p0.y, c=3 -> p1.y
// sh1(Q): pair1' = pair0 (rename); pair0' = {dpp(Qp1.y), Qp1.x}.
// 12 fma -> 6 v_pk_fma_f32. Seam: P[k+1]<-g, X[k+1]<-mu via cmp+cndmask.
// QE1/PE2/XE2 = slot lvalues of elements k+1,k+2; PSEAM/XSEAM = slot k+1.
#define STEP(QE1, PE2, XE2, PSEAM, XSEAM, LN1, LN2) do {                \
    float g  = -sF * isB;                                               \
    float sE = fmaf(g, sF, sB);              /* B_{k+1}[k+1] */         \
    isB = frcp_fast(sE);                                                \
    float mu = -sRt * isB;                                              \
    float rlF2 = rdlane(PE2, (LN2));         /* F_k[k+2]  */            \
    float rlB1 = rdlane(QE1, (LN1));         /* B_k[k+1]  */            \
    float rlR2 = rdlane(XE2, (LN2));         /* -R_k[k+2] */            \
    sF  = fmaf(g, rlB1, rlF2);               /* F_{k+1}[k+2] */         \
    float tB2 = fmaf(g, rlF2, rlB1);         /* B_{k+1}[k+2] */         \
    sRt = fmaf(mu, tB2, rlR2);               /* -R_{k+1}[k+2] */        \
    sB  = sE;                                                           \
    float2v g2 = {g, g}, mu2 = {mu, mu};                                \
    float shq = dpp0<0x138>(Qp1.y);          /* wave_shr:1 */           \
    float2v shQ0; shQ0.x = shq; shQ0.y = Qp1.x;                         \
    float2v shQ1 = Qp0;                                                 \
    float2v nQ0 = pkfma(g2, Pp0, shQ0);                                 \
    float2v nQ1 = pkfma(g2, Pp1, shQ1);                                 \
    float2v nP0 = pkfma(g2, shQ0, Pp0);                                 \
    float2v nP1 = pkfma(g2, shQ1, Pp1);                                 \
    Xp0 = pkfma(mu2, nQ0, Xp0);                                         \
    Xp1 = pkfma(mu2, nQ1, Xp1);                                         \
    bool bm = (lane == (LN1));               /* element k+1's lane */   \
    Pp0 = nP0; Pp1 = nP1; Qp0 = nQ0; Qp1 = nQ1;                         \
    PSEAM = bm ? g  : PSEAM;                                            \
    XSEAM = bm ? mu : XSEAM;                                            \
} while (0)

// One wave per batch. Schur solve of symmetric Toeplitz A v = b.
__global__ __launch_bounds__(64) void awloss_batch(
        const float* __restrict__ recon,
        const float* __restrict__ target,
        float* __restrict__ losses) {
    const int b    = blockIdx.x;
    const int lane = threadIdx.x;
    const bool l0  = (lane == 0);

    __shared__ __align__(16) float tgtp[576];   // t padded with zeros
    __shared__ __align__(16) float recp[576];   // rec at [127..382], zeros else

    const float4 tv4 = ((const float4*)(target + b * H))[lane];
    const float4 rv4 = ((const float4*)(recon  + b * H))[lane];

    #pragma unroll
    for (int c = 0; c < 9; ++c) { tgtp[c*64+lane] = 0.f; recp[c*64+lane] = 0.f; }
    __syncthreads();
    *(float4*)&tgtp[4*lane] = tv4;
    recp[127 + 4*lane + 0] = rv4.x;
    recp[127 + 4*lane + 1] = rv4.y;
    recp[127 + 4*lane + 2] = rv4.z;
    recp[127 + 4*lane + 3] = rv4.w;
    __syncthreads();

    // --- correlation r[d], b[d]; t[m] via uniform LDS broadcast (no readlane
    //     V->S hazards); pair-aligned substeps packed (v_pk_fma_f32).
    //     Per-accumulator fma order identical to R12 -> bitwise-same sums. ---
    float2v rp0 = {0.f,0.f}, rp1 = {0.f,0.f}, bp0 = {0.f,0.f}, bp1 = {0.f,0.f};
    float4 W0t = *(const float4*)&tgtp[4*lane];
    float4 W0r = *(const float4*)&recp[4*lane];
    for (int m0 = 0; m0 < 256; m0 += 4) {
        float4 W1t = *(const float4*)&tgtp[m0 + 4 + 4*lane];
        float4 W1r = *(const float4*)&recp[m0 + 4 + 4*lane];
        float4 tq  = *(const float4*)&tgtp[m0];          // uniform broadcast
        // m = m0 (pair-aligned -> pk)
        float2v tx = {tq.x, tq.x};
        rp0 = pkfma(tx, (float2v){W0t.x, W0t.y}, rp0);
        bp0 = pkfma(tx, (float2v){W0r.x, W0r.y}, bp0);
        rp1 = pkfma(tx, (float2v){W0t.z, W0t.w}, rp1);
        bp1 = pkfma(tx, (float2v){W0r.z, W0r.w}, bp1);
        // m = m0+1 (misaligned -> scalar)
        rp0.x = fmaf(tq.y, W0t.y, rp0.x); bp0.x = fmaf(tq.y, W0r.y, bp0.x);
        rp0.y = fmaf(tq.y, W0t.z, rp0.y); bp0.y = fmaf(tq.y, W0r.z, bp0.y);
        rp1.x = fmaf(tq.y, W0t.w, rp1.x); bp1.x = fmaf(tq.y, W0r.w, bp1.x);
        rp1.y = fmaf(tq.y, W1t.x, rp1.y); bp1.y = fmaf(tq.y, W1r.x, bp1.y);
        // m = m0+2 (pair-aligned -> pk)
        float2v tz = {tq.z, tq.z};
        rp0 = pkfma(tz, (float2v){W0t.z, W0t.w}, rp0);
        bp0 = pkfma(tz, (float2v){W0r.z, W0r.w}, bp0);
        rp1 = pkfma(tz, (float2v){W1t.x, W1t.y}, rp1);
        bp1 = pkfma(tz, (float2v){W1r.x, W1r.y}, bp1);
        // m = m0+3 (misaligned -> scalar)
        rp0.x = fmaf(tq.w, W0t.w, rp0.x); bp0.x = fmaf(tq.w, W0r.w, bp0.x);
        rp0.y = fmaf(tq.w, W1t.x, rp0.y); bp0.y = fmaf(tq.w, W1r.x, bp0.y);
        rp1.x = fmaf(tq.w, W1t.y, rp1.x); bp1.x = fmaf(tq.w, W1r.y, bp1.x);
        rp1.y = fmaf(tq.w, W1t.z, rp1.y); bp1.y = fmaf(tq.w, W1r.z, bp1.y);
        W0t = W1t; W0r = W1r;
    }

    // --- normalize; init packed stride-2 state ---
    float t0v = rdlane(rp0.x, 0) + EPS;
    float it0 = frcp_nr(t0v);
    float rho0 = rp0.x * it0;  rho0 = l0 ? 1.0f : rho0;   // rho[0] = 1
    float rho1 = rp0.y * it0;
    float rho2 = rp1.x * it0;
    float rho3 = rp1.y * it0;
    float2v Pp0 = {rho0, rho2}, Pp1 = {rho1, rho3};
    float2v Qp0 = Pp0,          Qp1 = Pp1;
    float bb0 = rdlane(bp0.x, 0) * it0;
    float X0 = fmaf(bb0, rho0, -(bp0.x * it0));   // -R_0 = bb0*rho - bb
    float X1 = fmaf(bb0, rho1, -(bp0.y * it0));
    float X2 = fmaf(bb0, rho2, -(bp1.x * it0));
    float X3 = fmaf(bb0, rho3, -(bp1.y * it0));
    if (l0) X0 = bb0;                             // x_0[0] = bb0
    float2v Xp0 = {X0, X2}, Xp1 = {X1, X3};

    float sF  = rdlane(Pp1.x, 0);                 // F_0[1] = rho[1] (slot 1)
    float sB  = 1.0f, isB = 1.0f;
    float sRt = rdlane(Xp1.x, 0);                 // -R_0[1]

    // --- 255 Schur steps, x4 unrolled; slot lvalues per k mod 4 ---
    for (int t = 0; t < 63; ++t) {
        STEP(Qp1.x, Pp0.y, Xp0.y, Pp1.x, Xp1.x, t,     t    );  // k=4t   s1=1 s2=2
        STEP(Qp0.y, Pp1.y, Xp1.y, Pp0.y, Xp0.y, t,     t    );  // k=4t+1 s1=2 s2=3
        STEP(Qp1.y, Pp0.x, Xp0.x, Pp1.y, Xp1.y, t,     t + 1);  // k=4t+2 s1=3 s2=0
        STEP(Qp0.x, Pp1.x, Xp1.x, Pp0.x, Xp0.x, t + 1, t + 1);  // k=4t+3 s1=0 s2=1
    }
    STEP(Qp1.x, Pp0.y, Xp0.y, Pp1.x, Xp1.x, 63, 63);            // k=252
    STEP(Qp0.y, Pp1.y, Xp1.y, Pp0.y, Xp0.y, 63, 63);            // k=253
    {   // k = 254: only mu and the X update matter (element 255 <- mu)
        float g  = -sF * isB;
        float sE = fmaf(g, sF, sB);
        float mu = -sRt * frcp_fast(sE);
        float2v g2 = {g, g}, mu2 = {mu, mu};
        float shq = dpp0<0x138>(Qp1.y);
        float2v shQ0; shQ0.x = shq; shQ0.y = Qp1.x;
        float2v shQ1 = Qp0;
        float2v nQ0 = pkfma(g2, Pp0, shQ0);
        float2v nQ1 = pkfma(g2, Pp1, shQ1);
        Xp0 = pkfma(mu2, nQ0, Xp0);
        Xp1 = pkfma(mu2, nQ1, Xp1);
        Xp1.y = (lane == 63) ? mu : Xp1.y;        // element 255, slot 3
    }

    // --- loss: 0.5*sqrt(sum((T*v)^2)/sum(v^2)); slot->value map ---
    float v0 = Xp0.x, v1 = Xp1.x, v2 = Xp0.y, v3 = Xp1.y;
    float vs[4] = {v0, v1, v2, v3};
    float sT = 0.f, sV = 0.f;
    const float dxg = 20.0f / 255.0f;
    #pragma unroll
    for (int c = 0; c < 4; ++c) {
        float v  = vs[c];
        float u  = -10.0f + dxg * (float)(4*lane + c) + 0.5f * dxg;
        float Ti = 1.0f - expf(-0.5f * u * u);   // T normalizers == 1.0f in f32
        float tw = Ti * v;
        sT += tw * tw;
        sV += v * v;
    }
    wave_red_sum2(sT, sV);
    if (l0) losses[b] = 0.5f * sqrtf(sT / sV);
}

// deterministic final reduction of 512 per-batch losses
__global__ __launch_bounds__(64) void awloss_reduce(
        const float* __restrict__ losses, float* __restrict__ out) {
    int lane = threadIdx.x;
    float s = 0.f;
    #pragma unroll
    for (int c = 0; c < 8; ++c) s += losses[c * 64 + lane];
    float d = 0.f;
    wave_red_sum2(s, d);
    if (lane == 0) out[0] = s;
}

extern "C" void kernel_launch(void* const* d_in, const int* in_sizes, int n_in,
                              void* d_out, int out_size, void* d_ws, size_t ws_size,
                              hipStream_t stream) {
    const float* recon  = (const float*)d_in[0];
    const float* target = (const float*)d_in[1];
    float* losses = (float*)d_ws;   // 512 floats
    float* out    = (float*)d_out;

    awloss_batch<<<512, 64, 0, stream>>>(recon, target, losses);
    awloss_reduce<<<1, 64, 0, stream>>>(losses, out);
}